// Round 2
// baseline (3034.399 us; speedup 1.0000x reference)
//
#include <hip/hip_runtime.h>

// convEP: 10-step EP relaxation.
//   s0' = rho(fc(s1));  s1' = rho(pool(conv0(s2)) + fc^T(s0));  s2' = rho(p2 + convT(unpool(s1, idx1)))
// All updates use PRE-update states. p2 = pool(conv1(data)) is loop-invariant.

#define BATCH 64

static __device__ __forceinline__ float rho_(float x) {
  return fminf(fmaxf(x, 0.0f), 1.0f);
}

// ---------------- K1: p2 = maxpool2x2(conv2d(data, conv1_w) + conv1_b) ----------------
// data [64,3,32,32] -> conv [64,64,32,32] -> pooled p2 [64,64,16,16]
// grid (64 b, 64 co), block 256 = 16x16 pooled positions
__global__ __launch_bounds__(256) void k_p2(
    const float* __restrict__ data, const float* __restrict__ w,
    const float* __restrict__ bias, float* __restrict__ p2) {
  __shared__ float ld[3][36][36];   // padded input image, 15.6 KB
  __shared__ float lw[80];
  int b = blockIdx.x, co = blockIdx.y, tid = threadIdx.x;
  for (int i = tid; i < 3 * 36 * 36; i += 256) {
    int ci = i / 1296, rem = i % 1296, y = rem / 36, x = rem % 36;
    int gy = y - 2, gx = x - 2;
    float v = 0.f;
    if (gy >= 0 && gy < 32 && gx >= 0 && gx < 32)
      v = data[(b * 3 + ci) * 1024 + gy * 32 + gx];
    ld[ci][y][x] = v;
  }
  if (tid < 75) lw[tid] = w[co * 75 + tid];
  __syncthreads();
  int ph = tid >> 4, pw = tid & 15;
  float bv = bias[co];
  float a00 = bv, a01 = bv, a10 = bv, a11 = bv;
  int ry = 2 * ph, rx = 2 * pw;   // padded coords of conv-out (2ph,2pw) tap (ky=kx=0)
  for (int ci = 0; ci < 3; ci++) {
#pragma unroll
    for (int ky = 0; ky < 5; ky++) {
#pragma unroll
      for (int kx = 0; kx < 5; kx++) {
        float wv = lw[(ci * 5 + ky) * 5 + kx];
        float i00 = ld[ci][ry + ky][rx + kx];
        float i01 = ld[ci][ry + ky][rx + kx + 1];
        float i10 = ld[ci][ry + ky + 1][rx + kx];
        float i11 = ld[ci][ry + ky + 1][rx + kx + 1];
        a00 += wv * i00; a01 += wv * i01; a10 += wv * i10; a11 += wv * i11;
      }
    }
  }
  float m = fmaxf(fmaxf(a00, a01), fmaxf(a10, a11));
  p2[((b * 64 + co) * 16 + ph) * 16 + pw] = m;
}

// ---------------- K2: conv0 + pool + argmax; writes p1 and u = unpool(s1_old, idx1) ----------------
// s2 [64,64,16,16] -> conv [64,128,16,16] -> p1 [64,128,8,8]; u [64,128,16,16]
// grid (64 b, 4 quadrant, 2 cgroup-of-64), block 256 = 16 pooled pos (4x4) x 16 slots (4 ch each)
__global__ __launch_bounds__(256) void k_conv0pool(
    const float* __restrict__ s2, const float* __restrict__ w0,
    const float* __restrict__ b0, const float* __restrict__ s1old,
    float* __restrict__ p1, float* __restrict__ u) {
  __shared__ float ls[64][12][12];   // 36.9 KB padded input tile
  int b = blockIdx.x, q = blockIdx.y, cg = blockIdx.z;
  int qy = q >> 1, qx = q & 1;
  int tid = threadIdx.x;
  const float* s2b = s2 + b * 64 * 256;
  for (int i = tid; i < 64 * 144; i += 256) {
    int c = i / 144, rem = i % 144, ty = rem / 12, tx = rem % 12;
    int gy = 8 * qy - 2 + ty, gx = 8 * qx - 2 + tx;
    float v = 0.f;
    if (gy >= 0 && gy < 16 && gx >= 0 && gx < 16) v = s2b[c * 256 + gy * 16 + gx];
    ls[c][ty][tx] = v;
  }
  __syncthreads();
  int pos = tid & 15, slot = tid >> 4;
  int lph = pos >> 2, lpw = pos & 3;
  int co0 = cg * 64 + slot * 4;
  float acc[4][4];   // [channel j][window wy*2+wx]
#pragma unroll
  for (int j = 0; j < 4; j++) {
    float bv = b0[co0 + j];
    acc[j][0] = acc[j][1] = acc[j][2] = acc[j][3] = bv;
  }
  const float* wp0 = w0 + (co0 + 0) * 1600;
  const float* wp1 = w0 + (co0 + 1) * 1600;
  const float* wp2 = w0 + (co0 + 2) * 1600;
  const float* wp3 = w0 + (co0 + 3) * 1600;
  int ry = 2 * lph, rx = 2 * lpw;
  for (int ci = 0; ci < 64; ci++) {
#pragma unroll
    for (int ky = 0; ky < 5; ky++) {
#pragma unroll
      for (int kx = 0; kx < 5; kx++) {
        float i00 = ls[ci][ry + ky][rx + kx];
        float i01 = ls[ci][ry + ky][rx + kx + 1];
        float i10 = ls[ci][ry + ky + 1][rx + kx];
        float i11 = ls[ci][ry + ky + 1][rx + kx + 1];
        int wi = ci * 25 + ky * 5 + kx;
        float wv;
        wv = wp0[wi]; acc[0][0] += wv * i00; acc[0][1] += wv * i01; acc[0][2] += wv * i10; acc[0][3] += wv * i11;
        wv = wp1[wi]; acc[1][0] += wv * i00; acc[1][1] += wv * i01; acc[1][2] += wv * i10; acc[1][3] += wv * i11;
        wv = wp2[wi]; acc[2][0] += wv * i00; acc[2][1] += wv * i01; acc[2][2] += wv * i10; acc[2][3] += wv * i11;
        wv = wp3[wi]; acc[3][0] += wv * i00; acc[3][1] += wv * i01; acc[3][2] += wv * i10; acc[3][3] += wv * i11;
      }
    }
  }
  int ph = qy * 4 + lph, pw = qx * 4 + lpw;
#pragma unroll
  for (int j = 0; j < 4; j++) {
    int co = co0 + j;
    // first-occurrence argmax (matches jnp.argmax tie-breaking; window order (wy,wx))
    float m = acc[j][0]; int id = 0;
    if (acc[j][1] > m) { m = acc[j][1]; id = 1; }
    if (acc[j][2] > m) { m = acc[j][2]; id = 2; }
    if (acc[j][3] > m) { m = acc[j][3]; id = 3; }
    int pidx = ((b * 128 + co) * 8 + ph) * 8 + pw;
    p1[pidx] = m;
    float sv = s1old[pidx];
    float* ub = u + ((b * 128 + co) * 16 + 2 * ph) * 16 + 2 * pw;
    ub[0]  = (id == 0) ? sv : 0.f;
    ub[1]  = (id == 1) ? sv : 0.f;
    ub[16] = (id == 2) ? sv : 0.f;
    ub[17] = (id == 3) ? sv : 0.f;
  }
}

// ---------------- K3: up = conv(u, tw); s2_new = rho(p2 + up) ----------------
// tw[o][c][ky][kx] = conv0_w[c][o][4-ky][4-kx]  =>  up[o,y,x] = sum_c,k W0[c][o][ky][kx]*u[c, y+2-ky, x+2-kx]
// conv0_w is [128,64,5,5]: W0[c'][o][k] has c'-stride 1600, o-stride 25.
// grid (64 b, 4 quadrant), block 256 = 16 spatial groups (2x2 of 8x8 quad) x 16 slots (4 out-ch each)
__global__ __launch_bounds__(256) void k_convT(
    const float* __restrict__ u, const float* __restrict__ w0,
    const float* __restrict__ p2, float* __restrict__ s2new) {
  __shared__ float lu[64][12][12];   // 36.9 KB, one 64-channel chunk at a time
  int b = blockIdx.x, q = blockIdx.y;
  int y0 = (q >> 1) * 8, x0 = (q & 1) * 8;
  int tid = threadIdx.x;
  int sg = tid & 15, slot = tid >> 4;
  int ly0 = (sg >> 2) * 2, lx0 = (sg & 3) * 2;
  int o0 = slot * 4;
  float acc[4][4];   // [out-ch j][wy*2+wx]
#pragma unroll
  for (int j = 0; j < 4; j++) acc[j][0] = acc[j][1] = acc[j][2] = acc[j][3] = 0.f;

  for (int ch = 0; ch < 2; ch++) {
    __syncthreads();   // protect lu from previous chunk's readers
    const float* ub = u + (b * 128 + ch * 64) * 256;
    for (int i = tid; i < 64 * 144; i += 256) {
      int c = i / 144, rem = i % 144, ty = rem / 12, tx = rem % 12;
      int gy = y0 - 2 + ty, gx = x0 - 2 + tx;
      float v = 0.f;
      if (gy >= 0 && gy < 16 && gx >= 0 && gx < 16) v = ub[c * 256 + gy * 16 + gx];
      lu[c][ty][tx] = v;
    }
    __syncthreads();
    for (int c = 0; c < 64; c++) {
      const float* wc = w0 + (ch * 64 + c) * 1600 + o0 * 25;   // W0[c'][o][k]: c'-stride 1600, o-stride 25
#pragma unroll
      for (int ky = 0; ky < 5; ky++) {
#pragma unroll
        for (int kx = 0; kx < 5; kx++) {
          float i00 = lu[c][ly0 + 4 - ky][lx0 + 4 - kx];
          float i01 = lu[c][ly0 + 4 - ky][lx0 + 5 - kx];
          float i10 = lu[c][ly0 + 5 - ky][lx0 + 4 - kx];
          float i11 = lu[c][ly0 + 5 - ky][lx0 + 5 - kx];
          int k = ky * 5 + kx;
          float wv;
          wv = wc[0 * 25 + k]; acc[0][0] += wv * i00; acc[0][1] += wv * i01; acc[0][2] += wv * i10; acc[0][3] += wv * i11;
          wv = wc[1 * 25 + k]; acc[1][0] += wv * i00; acc[1][1] += wv * i01; acc[1][2] += wv * i10; acc[1][3] += wv * i11;
          wv = wc[2 * 25 + k]; acc[2][0] += wv * i00; acc[2][1] += wv * i01; acc[2][2] += wv * i10; acc[2][3] += wv * i11;
          wv = wc[3 * 25 + k]; acc[3][0] += wv * i00; acc[3][1] += wv * i01; acc[3][2] += wv * i10; acc[3][3] += wv * i11;
        }
      }
    }
  }
#pragma unroll
  for (int j = 0; j < 4; j++) {
    int o = o0 + j;
#pragma unroll
    for (int wy = 0; wy < 2; wy++)
#pragma unroll
      for (int wx = 0; wx < 2; wx++) {
        int y = y0 + ly0 + wy, x = x0 + lx0 + wx;
        int idx = ((b * 64 + o) * 16 + y) * 16 + x;
        s2new[idx] = rho_(p2[idx] + acc[j][wy * 2 + wx]);
      }
  }
}

// ---------------- K4: s1_new = rho(p1 + reshape(s0_old @ fc_w)) ----------------
// grid 2048, block 256; i over 64*8192 (flat == [B,128,8,8] channel-major)
__global__ __launch_bounds__(256) void k_s1fc(
    const float* __restrict__ p1, const float* __restrict__ s0old,
    const float* __restrict__ fcw, float* __restrict__ s1new) {
  int i = blockIdx.x * 256 + threadIdx.x;
  int b = i >> 13, j = i & 8191;
  float a = p1[i];
#pragma unroll
  for (int k = 0; k < 10; k++) a += s0old[b * 10 + k] * fcw[k * 8192 + j];
  s1new[i] = rho_(a);
}

// ---------------- K5: s0_new = rho(s1_old_flat @ fc_w^T + fc_b) ----------------
// grid 64 (one block per batch), block 256
__global__ __launch_bounds__(256) void k_s0fc(
    const float* __restrict__ s1old, const float* __restrict__ fcw,
    const float* __restrict__ fcb, float* __restrict__ s0new) {
  __shared__ float red[10][256];
  int b = blockIdx.x, tid = threadIdx.x;
  float acc[10];
#pragma unroll
  for (int o = 0; o < 10; o++) acc[o] = 0.f;
  const float* sb = s1old + b * 8192;
  for (int i = tid; i < 8192; i += 256) {
    float v = sb[i];
#pragma unroll
    for (int o = 0; o < 10; o++) acc[o] += v * fcw[o * 8192 + i];
  }
#pragma unroll
  for (int o = 0; o < 10; o++) red[o][tid] = acc[o];
  __syncthreads();
  for (int s = 128; s > 0; s >>= 1) {
    if (tid < s) {
#pragma unroll
      for (int o = 0; o < 10; o++) red[o][tid] += red[o][tid + s];
    }
    __syncthreads();
  }
  if (tid < 10) s0new[b * 10 + tid] = rho_(red[tid][0] + fcb[tid]);
}

extern "C" void kernel_launch(void* const* d_in, const int* in_sizes, int n_in,
                              void* d_out, int out_size, void* d_ws, size_t ws_size,
                              hipStream_t stream) {
  const float* data   = (const float*)d_in[0];
  const float* s0init = (const float*)d_in[1];   // zeros
  const float* s1init = (const float*)d_in[2];   // zeros
  const float* s2init = (const float*)d_in[3];   // zeros
  const float* conv0w = (const float*)d_in[4];
  const float* conv0b = (const float*)d_in[5];
  const float* conv1w = (const float*)d_in[6];
  const float* conv1b = (const float*)d_in[7];
  const float* fcw    = (const float*)d_in[8];
  const float* fcb    = (const float*)d_in[9];

  // workspace layout (floats); total 6,817,024 floats = ~26 MB
  float* p = (float*)d_ws;
  float* s0buf[2] = {p, p + 640};            p += 1280;
  float* s1buf[2] = {p, p + 524288};         p += 1048576;
  float* s2buf[2] = {p, p + 1048576};        p += 2097152;
  float* p1 = p;                             p += 524288;
  float* p2 = p;                             p += 1048576;
  float* u  = p;                             p += 2097152;

  // loop-invariant: p2 = maxpool(conv1(data))
  k_p2<<<dim3(64, 64), 256, 0, stream>>>(data, conv1w, conv1b, p2);

  const float* s0o = s0init;
  const float* s1o = s1init;
  const float* s2o = s2init;
  float* outp = (float*)d_out;

  for (int t = 0; t < 10; t++) {
    int nb = t & 1;
    float* s0w = s0buf[nb];
    float* s1w = s1buf[nb];
    float* s2w = s2buf[nb];

    // conv0(s2_old) -> pool/argmax -> p1, u=unpool(s1_old, idx1)
    k_conv0pool<<<dim3(64, 4, 2), 256, 0, stream>>>(s2o, conv0w, conv0b, s1o, p1, u);
    // s0_new = rho(fc(s1_old))
    k_s0fc<<<64, 256, 0, stream>>>(s1o, fcw, fcb, s0w);
    // s1_new = rho(p1 + fc^T(s0_old))
    k_s1fc<<<2048, 256, 0, stream>>>(p1, s0o, fcw, s1w);
    // s2_new = rho(p2 + convT(u))
    k_convT<<<dim3(64, 4), 256, 0, stream>>>(u, conv0w, p2, s2w);

    s0o = s0w; s1o = s1w; s2o = s2w;

    if (t == 6) {   // PRED_T snapshot (post-update states)
      hipMemcpyAsync(outp + 1573504, s0w, 640 * sizeof(float),     hipMemcpyDeviceToDevice, stream);
      hipMemcpyAsync(outp + 1574144, s1w, 524288 * sizeof(float),  hipMemcpyDeviceToDevice, stream);
      hipMemcpyAsync(outp + 2098432, s2w, 1048576 * sizeof(float), hipMemcpyDeviceToDevice, stream);
    }
  }

  // final states
  hipMemcpyAsync(outp + 0,      s0o, 640 * sizeof(float),     hipMemcpyDeviceToDevice, stream);
  hipMemcpyAsync(outp + 640,    s1o, 524288 * sizeof(float),  hipMemcpyDeviceToDevice, stream);
  hipMemcpyAsync(outp + 524928, s2o, 1048576 * sizeof(float), hipMemcpyDeviceToDevice, stream);
}

// Round 3
// 2342.440 us; speedup vs baseline: 1.2954x; 1.2954x over previous
//
#include <hip/hip_runtime.h>

// convEP: 10-step EP relaxation.
//   s0' = rho(fc(s1));  s1' = rho(pool(conv0(s2)) + fc^T(s0));  s2' = rho(p2 + convT(unpool(s1, idx1)))
// All updates use PRE-update states. p2 = pool(conv1(data)) is loop-invariant.
// Conv kernels: lanes = output channels (weights coalesced via transposed layout,
// LDS input reads are same-address broadcasts), 4x4 spatial tile per thread.

static __device__ __forceinline__ float rho_(float x) {
  return fminf(fmaxf(x, 0.0f), 1.0f);
}

// ---------------- K0: one-time weight transposes ----------------
// wT0[(ci*25+k)*128 + co] = conv0w[(co*64+ci)*25 + k]   (for forward conv0, lanes=co)
// wT1[(cp*25+k)*64  + o ] = conv0w[(cp*64+o )*25 + k]   (for convT, lanes=o)
__global__ __launch_bounds__(256) void k_wtrans(
    const float* __restrict__ w0, float* __restrict__ wT0, float* __restrict__ wT1) {
  int i = blockIdx.x * 256 + threadIdx.x;
  if (i >= 204800) return;
  {
    int co = i & 127, rest = i >> 7;
    int k = rest % 25, ci = rest / 25;
    wT0[i] = w0[(co * 64 + ci) * 25 + k];
  }
  {
    int o = i & 63, rest = i >> 6;
    int k = rest % 25, cp = rest / 25;
    wT1[i] = w0[(cp * 64 + o) * 25 + k];
  }
}

// ---------------- K1: p2 = maxpool2x2(conv2d(data, conv1_w) + conv1_b) ----------------
// (runs once; not perf-critical)
__global__ __launch_bounds__(256) void k_p2(
    const float* __restrict__ data, const float* __restrict__ w,
    const float* __restrict__ bias, float* __restrict__ p2) {
  __shared__ float ld[3][36][36];
  __shared__ float lw[80];
  int b = blockIdx.x, co = blockIdx.y, tid = threadIdx.x;
  for (int i = tid; i < 3 * 36 * 36; i += 256) {
    int ci = i / 1296, rem = i % 1296, y = rem / 36, x = rem % 36;
    int gy = y - 2, gx = x - 2;
    float v = 0.f;
    if (gy >= 0 && gy < 32 && gx >= 0 && gx < 32)
      v = data[(b * 3 + ci) * 1024 + gy * 32 + gx];
    ld[ci][y][x] = v;
  }
  if (tid < 75) lw[tid] = w[co * 75 + tid];
  __syncthreads();
  int ph = tid >> 4, pw = tid & 15;
  float bv = bias[co];
  float a00 = bv, a01 = bv, a10 = bv, a11 = bv;
  int ry = 2 * ph, rx = 2 * pw;
  for (int ci = 0; ci < 3; ci++) {
#pragma unroll
    for (int ky = 0; ky < 5; ky++) {
#pragma unroll
      for (int kx = 0; kx < 5; kx++) {
        float wv = lw[(ci * 5 + ky) * 5 + kx];
        a00 += wv * ld[ci][ry + ky][rx + kx];
        a01 += wv * ld[ci][ry + ky][rx + kx + 1];
        a10 += wv * ld[ci][ry + ky + 1][rx + kx];
        a11 += wv * ld[ci][ry + ky + 1][rx + kx + 1];
      }
    }
  }
  float m = fmaxf(fmaxf(a00, a01), fmaxf(a10, a11));
  p2[((b * 64 + co) * 16 + ph) * 16 + pw] = m;
}

// ---------------- K2: conv0 + pool + argmax; writes p1 and u = unpool(s1_old, idx1) ----------------
// grid (64 b, 4 quad, 2 cg), block 256 = 64 co-lanes x 4 quarters (each 4x4 conv = 2x2 pooled)
__global__ __launch_bounds__(256) void k_conv0pool(
    const float* __restrict__ s2, const float* __restrict__ wT0,
    const float* __restrict__ b0, const float* __restrict__ s1old,
    float* __restrict__ p1, float* __restrict__ u) {
  __shared__ float T[64 * 12 * 16];   // 48 KB: 64 ch x 12 rows x 16-padded cols
  int b = blockIdx.x, q = blockIdx.y, cg = blockIdx.z;
  int qy = q >> 1, qx = q & 1;
  int tid = threadIdx.x;
  const float* s2b = s2 + b * 64 * 256;
  for (int i = tid; i < 64 * 144; i += 256) {
    int c = i / 144, rem = i % 144, ty = rem / 12, tx = rem % 12;
    int gy = 8 * qy - 2 + ty, gx = 8 * qx - 2 + tx;
    float v = 0.f;
    if (gy >= 0 && gy < 16 && gx >= 0 && gx < 16) v = s2b[c * 256 + gy * 16 + gx];
    T[(c * 12 + ty) * 16 + tx] = v;
  }
  __syncthreads();
  int lane = tid & 63, quarter = tid >> 6;
  int qr = quarter >> 1, qc = quarter & 1;
  int co = cg * 64 + lane;
  float bv = b0[co];
  float acc[4][4];
#pragma unroll
  for (int r = 0; r < 4; r++)
#pragma unroll
    for (int x = 0; x < 4; x++) acc[r][x] = bv;

  for (int ci = 0; ci < 64; ci++) {
    float w[25];
    const float* wp = wT0 + ci * 25 * 128 + co;
#pragma unroll
    for (int k = 0; k < 25; k++) w[k] = wp[k * 128];
    const float4* Trow = (const float4*)(T + (ci * 12 + qr * 4) * 16 + qc * 4);
#pragma unroll
    for (int rr = 0; rr < 8; rr++) {
      float4 a0 = Trow[rr * 4];
      float4 a1 = Trow[rr * 4 + 1];
      float in[8] = {a0.x, a0.y, a0.z, a0.w, a1.x, a1.y, a1.z, a1.w};
#pragma unroll
      for (int r = 0; r < 4; r++) {
        int ky = rr - r;            // out row r uses input row r+ky
        if (ky >= 0 && ky <= 4) {
#pragma unroll
          for (int kx = 0; kx < 5; kx++) {
            float wv = w[ky * 5 + kx];
#pragma unroll
            for (int x = 0; x < 4; x++) acc[r][x] += wv * in[x + kx];
          }
        }
      }
    }
  }
  // pool 4x4 conv -> 2x2 pooled cells, first-occurrence argmax, window order (wy,wx)
#pragma unroll
  for (int py = 0; py < 2; py++) {
#pragma unroll
    for (int px = 0; px < 2; px++) {
      float v0 = acc[2 * py][2 * px], v1 = acc[2 * py][2 * px + 1];
      float v2 = acc[2 * py + 1][2 * px], v3 = acc[2 * py + 1][2 * px + 1];
      float m = v0; int id = 0;
      if (v1 > m) { m = v1; id = 1; }
      if (v2 > m) { m = v2; id = 2; }
      if (v3 > m) { m = v3; id = 3; }
      int ph = qy * 4 + qr * 2 + py, pw = qx * 4 + qc * 2 + px;
      int pidx = ((b * 128 + co) * 8 + ph) * 8 + pw;
      p1[pidx] = m;
      float sv = s1old[pidx];
      float* ub = u + ((b * 128 + co) * 16 + 2 * ph) * 16 + 2 * pw;
      ub[0]  = (id == 0) ? sv : 0.f;
      ub[1]  = (id == 1) ? sv : 0.f;
      ub[16] = (id == 2) ? sv : 0.f;
      ub[17] = (id == 3) ? sv : 0.f;
    }
  }
}

// ---------------- K3: convT partial: upPart[ch] = conv(u[ch*64:(ch+1)*64], tw) ----------------
// up[o,y,x] = sum_{c,ky,kx} W0[c][o][ky][kx] * u[c, y+2-ky, x+2-kx]
// grid (64 b, 4 quad, 2 cchunk), block 256 = 64 o-lanes x 4 quarters (4x4 each)
__global__ __launch_bounds__(256) void k_convT(
    const float* __restrict__ u, const float* __restrict__ wT1,
    float* __restrict__ upPart) {
  __shared__ float T[64 * 12 * 16];   // 48 KB
  int b = blockIdx.x, q = blockIdx.y, ch = blockIdx.z;
  int qy = q >> 1, qx = q & 1;
  int tid = threadIdx.x;
  const float* ub = u + (b * 128 + ch * 64) * 256;
  for (int i = tid; i < 64 * 144; i += 256) {
    int c = i / 144, rem = i % 144, ty = rem / 12, tx = rem % 12;
    int gy = 8 * qy - 2 + ty, gx = 8 * qx - 2 + tx;
    float v = 0.f;
    if (gy >= 0 && gy < 16 && gx >= 0 && gx < 16) v = ub[c * 256 + gy * 16 + gx];
    T[(c * 12 + ty) * 16 + tx] = v;
  }
  __syncthreads();
  int lane = tid & 63, quarter = tid >> 6;
  int qr = quarter >> 1, qc = quarter & 1;
  float acc[4][4];
#pragma unroll
  for (int r = 0; r < 4; r++)
#pragma unroll
    for (int x = 0; x < 4; x++) acc[r][x] = 0.f;

  for (int cc = 0; cc < 64; cc++) {
    int c = ch * 64 + cc;
    float w[25];
    const float* wp = wT1 + c * 25 * 64 + lane;
#pragma unroll
    for (int k = 0; k < 25; k++) w[k] = wp[k * 64];
    const float4* Trow = (const float4*)(T + (cc * 12 + qr * 4) * 16 + qc * 4);
#pragma unroll
    for (int rr = 0; rr < 8; rr++) {
      float4 a0 = Trow[rr * 4];
      float4 a1 = Trow[rr * 4 + 1];
      float in[8] = {a0.x, a0.y, a0.z, a0.w, a1.x, a1.y, a1.z, a1.w};
#pragma unroll
      for (int r = 0; r < 4; r++) {
        int ky = r - rr + 4;        // out row r uses input row r+4-ky (tile-rel rr)
        if (ky >= 0 && ky <= 4) {
#pragma unroll
          for (int kx = 0; kx < 5; kx++) {
            float wv = w[ky * 5 + kx];
#pragma unroll
            for (int x = 0; x < 4; x++) acc[r][x] += wv * in[x + 4 - kx];
          }
        }
      }
    }
  }
  float* op = upPart + ch * 1048576 + (b * 64 + lane) * 256;
#pragma unroll
  for (int r = 0; r < 4; r++) {
    int y = qy * 8 + qr * 4 + r;
#pragma unroll
    for (int x = 0; x < 4; x++) {
      int xx = qx * 8 + qc * 4 + x;
      op[y * 16 + xx] = acc[r][x];
    }
  }
}

// ---------------- K3b: s2_new = rho(p2 + up0 + up1) ----------------
__global__ __launch_bounds__(256) void k_s2comb(
    const float* __restrict__ p2, const float* __restrict__ a,
    const float* __restrict__ b, float* __restrict__ s2new) {
  int i = blockIdx.x * 256 + threadIdx.x;   // over 262144 float4s
  float4 p = ((const float4*)p2)[i];
  float4 av = ((const float4*)a)[i];
  float4 bv = ((const float4*)b)[i];
  float4 o;
  o.x = rho_(p.x + av.x + bv.x);
  o.y = rho_(p.y + av.y + bv.y);
  o.z = rho_(p.z + av.z + bv.z);
  o.w = rho_(p.w + av.w + bv.w);
  ((float4*)s2new)[i] = o;
}

// ---------------- K4: s1_new = rho(p1 + reshape(s0_old @ fc_w)) ----------------
__global__ __launch_bounds__(256) void k_s1fc(
    const float* __restrict__ p1, const float* __restrict__ s0old,
    const float* __restrict__ fcw, float* __restrict__ s1new) {
  int i = blockIdx.x * 256 + threadIdx.x;
  int b = i >> 13, j = i & 8191;
  float a = p1[i];
#pragma unroll
  for (int k = 0; k < 10; k++) a += s0old[b * 10 + k] * fcw[k * 8192 + j];
  s1new[i] = rho_(a);
}

// ---------------- K5: s0_new = rho(s1_old_flat @ fc_w^T + fc_b) ----------------
__global__ __launch_bounds__(256) void k_s0fc(
    const float* __restrict__ s1old, const float* __restrict__ fcw,
    const float* __restrict__ fcb, float* __restrict__ s0new) {
  __shared__ float red[10][256];
  int b = blockIdx.x, tid = threadIdx.x;
  float acc[10];
#pragma unroll
  for (int o = 0; o < 10; o++) acc[o] = 0.f;
  const float* sb = s1old + b * 8192;
  for (int i = tid; i < 8192; i += 256) {
    float v = sb[i];
#pragma unroll
    for (int o = 0; o < 10; o++) acc[o] += v * fcw[o * 8192 + i];
  }
#pragma unroll
  for (int o = 0; o < 10; o++) red[o][tid] = acc[o];
  __syncthreads();
  for (int s = 128; s > 0; s >>= 1) {
    if (tid < s) {
#pragma unroll
      for (int o = 0; o < 10; o++) red[o][tid] += red[o][tid + s];
    }
    __syncthreads();
  }
  if (tid < 10) s0new[b * 10 + tid] = rho_(red[tid][0] + fcb[tid]);
}

extern "C" void kernel_launch(void* const* d_in, const int* in_sizes, int n_in,
                              void* d_out, int out_size, void* d_ws, size_t ws_size,
                              hipStream_t stream) {
  const float* data   = (const float*)d_in[0];
  const float* s0init = (const float*)d_in[1];   // zeros
  const float* s1init = (const float*)d_in[2];   // zeros
  const float* s2init = (const float*)d_in[3];   // zeros
  const float* conv0w = (const float*)d_in[4];
  const float* conv1w = (const float*)d_in[6];
  const float* conv1b = (const float*)d_in[7];
  const float* conv0b = (const float*)d_in[5];
  const float* fcw    = (const float*)d_in[8];
  const float* fcb    = (const float*)d_in[9];

  // workspace layout (floats); ~9.33M floats = ~37.3 MB
  float* p = (float*)d_ws;
  float* s0buf[2] = {p, p + 640};            p += 1280;
  float* s1buf[2] = {p, p + 524288};         p += 1048576;
  float* s2buf[2] = {p, p + 1048576};        p += 2097152;
  float* p1 = p;                             p += 524288;
  float* p2 = p;                             p += 1048576;
  float* u  = p;                             p += 2097152;
  float* wT0 = p;                            p += 204800;
  float* wT1 = p;                            p += 204800;
  float* upPart = p;                         p += 2097152;   // 2 chunks x 1M floats

  // one-time: weight transposes + loop-invariant p2
  k_wtrans<<<800, 256, 0, stream>>>(conv0w, wT0, wT1);
  k_p2<<<dim3(64, 64), 256, 0, stream>>>(data, conv1w, conv1b, p2);

  const float* s0o = s0init;
  const float* s1o = s1init;
  const float* s2o = s2init;
  float* outp = (float*)d_out;

  for (int t = 0; t < 10; t++) {
    int nb = t & 1;
    float* s0w = s0buf[nb];
    float* s1w = s1buf[nb];
    float* s2w = s2buf[nb];

    k_conv0pool<<<dim3(64, 4, 2), 256, 0, stream>>>(s2o, wT0, conv0b, s1o, p1, u);
    k_s0fc<<<64, 256, 0, stream>>>(s1o, fcw, fcb, s0w);
    k_s1fc<<<2048, 256, 0, stream>>>(p1, s0o, fcw, s1w);
    k_convT<<<dim3(64, 4, 2), 256, 0, stream>>>(u, wT1, upPart);
    k_s2comb<<<1024, 256, 0, stream>>>(p2, upPart, upPart + 1048576, s2w);

    s0o = s0w; s1o = s1w; s2o = s2w;

    if (t == 6) {   // PRED_T snapshot (post-update states)
      hipMemcpyAsync(outp + 1573504, s0w, 640 * sizeof(float),     hipMemcpyDeviceToDevice, stream);
      hipMemcpyAsync(outp + 1574144, s1w, 524288 * sizeof(float),  hipMemcpyDeviceToDevice, stream);
      hipMemcpyAsync(outp + 2098432, s2w, 1048576 * sizeof(float), hipMemcpyDeviceToDevice, stream);
    }
  }

  // final states
  hipMemcpyAsync(outp + 0,      s0o, 640 * sizeof(float),     hipMemcpyDeviceToDevice, stream);
  hipMemcpyAsync(outp + 640,    s1o, 524288 * sizeof(float),  hipMemcpyDeviceToDevice, stream);
  hipMemcpyAsync(outp + 524928, s2o, 1048576 * sizeof(float), hipMemcpyDeviceToDevice, stream);
}